// Round 15
// baseline (47.074 us; speedup 1.0000x reference)
//
#include <hip/hip_runtime.h>
#include <stdint.h>

#define BB 4
#define HH 128
#define WW 128
#define AA 15
#define GG 32
#define NPOS (BB*HH*WW*AA)       // 983040
#define NBLK1 240                // k_main blocks (1 per CU, 4096 pos each)
#define POSB 4096
#define NCHUNK (NPOS/1024)       // 960
#define NB 256                   // fine bins over (0.5, 1.0]
#define NBKT 16                  // coarse buckets = NB/16
#define SLOTB 2048               // slots per (block,bucket)
#define TOPK 100
#define CCAP 2048

// workspace layout (bytes) — identical to r5/r13/r14 (proven). Everything
// k_finish reads is written unconditionally by k_main each call -> no zero-init.
#define OFF_CHUNK 0              // uint32[960]
#define OFF_FLAG  4096           // uint8[NPOS]
#define OFF_HISTB 987136         // uint32[240*256]
#define OFF_BCNT  1232896        // uint32[240*16]
#define OFF_CAND  1248256        // uint2[240*16*2048]  (~63 MB)

__device__ __forceinline__ int fine_bin(float v) {
    int b = (int)__builtin_fmaf(v, 512.0f, -256.0f);
    b = b < 0 ? 0 : (b > NB-1 ? NB-1 : b);
    return b;
}

// Pass 1 — r14 byte-identical EXCEPT: g-loop unroll full -> 2.
// Hypothesis: the fully-unrolled body (~32KB of code) thrashes the 32KB L1I;
// front-end fetch stalls are occupancy/LDS/VALU-insensitive, matching the
// r9/r13/r14 nulls. Compact 2-body loop stays I-cache-resident.
__global__ __launch_bounds__(1024) void k_main(const float4* __restrict__ props,
                                               const float4* __restrict__ gt4,
                                               uint8_t* __restrict__ ws) {
    __shared__ float4 s_gt4[GG];
    __shared__ float  s_ga[GG];
    __shared__ uint32_t s_hist[NB];
    __shared__ uint32_t s_bcnt[NBKT];
    __shared__ uint32_t s_red[64];
    int tid = threadIdx.x;
    if (tid < GG) s_gt4[tid] = gt4[tid];
    if (tid < NB) s_hist[tid] = 0u;
    if (tid < NBKT) s_bcnt[tid] = 0u;
    __syncthreads();
    if (tid < GG) {
        float4 G = s_gt4[tid];
        s_ga[tid] = (G.z - G.x) * (G.w - G.y);     // identical expr to reference
    }
    __syncthreads();

    uint2* candB = (uint2*)(ws + OFF_CAND) + (size_t)blockIdx.x * NBKT * SLOTB;

    for (int k = 0; k < 4; ++k) {
        int pos = blockIdx.x * POSB + k*1024 + tid;
        float4 p = props[pos];                      // (y1,x1,y2,x2)
        float area_p = (p.z - p.x) * (p.w - p.y);
        int bhw = pos / AA;
        int a = pos - bhw * AA;
        bool neg = true;
        #pragma unroll 2
        for (int g = 0; g < GG; ++g) {
            float4 G = s_gt4[g];                    // one ds_read_b128
            float ih = fmaxf(fminf(p.z, G.z) - fmaxf(p.x, G.x), 0.0f);
            float iw = fmaxf(fminf(p.w, G.w) - fmaxf(p.y, G.y), 0.0f);
            float inter = ih * iw;
            float apga = area_p + s_ga[g];          // == reference (area_p+area_g)
            // conservative screen: inter > 0.28*apga  <=>  v > ~0.3889;
            // every pair with exact v >= 0.4 (and a fortiori > 0.5) passes.
            if (inter > 0.28f * apga) {
                float u = apga - inter;             // bit-identical reference u
                float v = inter / u;                // exact reference value
                neg = neg && (v < 0.4f);
                if (v > 0.5f) {
                    int bin = fine_bin(v);
                    atomicAdd(&s_hist[bin], 1u);    // UNCAPPED count
                    int bkt = bin >> 4;
                    uint32_t slot = atomicAdd(&s_bcnt[bkt], 1u);
                    if (slot < SLOTB)
                        candB[bkt*SLOTB + slot] =
                            make_uint2(__float_as_uint(v),
                                       (uint32_t)((bhw*GG + g)*AA + a));
                }
            }
        }
        ws[OFF_FLAG + pos] = neg ? 1 : 0;
        unsigned long long bal = __ballot(neg);
        if ((tid & 63) == 0) s_red[k*16 + (tid >> 6)] = (uint32_t)__popcll(bal);
    }
    __syncthreads();
    if (tid < 4) {
        uint32_t s = 0;
        #pragma unroll
        for (int w = 0; w < 16; ++w) s += s_red[tid*16 + w];
        ((uint32_t*)(ws + OFF_CHUNK))[blockIdx.x*4 + tid] = s;
    }
    if (tid < NB) ((uint32_t*)(ws + OFF_HISTB))[blockIdx.x*NB + tid] = s_hist[tid];
    if (tid < NBKT) {
        uint32_t c = s_bcnt[tid]; if (c > SLOTB) c = SLOTB;
        ((uint32_t*)(ws + OFF_BCNT))[blockIdx.x*NBKT + tid] = c;
    }
}

__device__ __forceinline__ uint32_t incl_scan(uint32_t* s, int tid, uint32_t v) {
    s[tid] = v; __syncthreads();
    for (int st = 1; st < 1024; st <<= 1) {
        uint32_t t = (tid >= st) ? s[tid - st] : 0u;
        __syncthreads();
        s[tid] += t;
        __syncthreads();
    }
    return s[tid];
}

// Pass 2 (r5/r13/r14-verbatim, proven): hist-sum -> T/npos, gather+rank,
// negatives, output.
__global__ __launch_bounds__(1024) void k_finish(const float* __restrict__ props,
                                                 const float* __restrict__ gt,
                                                 const float* __restrict__ cls,
                                                 uint8_t* __restrict__ ws,
                                                 float* __restrict__ out) {
    __shared__ uint32_t sdata[1024];
    __shared__ uint32_t s_tot[NB];
    __shared__ float sc_v[CCAP];
    __shared__ int   sc_i[CCAP];
    __shared__ int s_posI[128];
    __shared__ int s_negI[128];
    __shared__ float s_gt[GG*4];
    __shared__ int s_T, s_M, s_c2, s_negTot;

    int tid = threadIdx.x;
    if (tid < GG*4) s_gt[tid] = gt[tid];
    if (tid == 0) { s_T = 0; s_c2 = 0; }

    // --- 1. total histogram: 4 partial sums of 60 blocks each ---
    {
        const uint32_t* histB = (const uint32_t*)(ws + OFF_HISTB);
        int part = tid >> 8;          // 0..3
        int t = tid & 255;
        uint32_t ssum = 0;
        for (int blk = part*60; blk < part*60 + 60; ++blk) ssum += histB[blk*NB + t];
        sdata[tid] = ssum;
        __syncthreads();
        if (tid < NB) s_tot[tid] = sdata[tid] + sdata[tid+256] + sdata[tid+512] + sdata[tid+768];
        __syncthreads();
    }

    // --- 2. suffix counts -> M, T ---
    if (tid < NB) sdata[tid] = s_tot[NB-1 - tid];     // reversed
    __syncthreads();
    for (int st = 1; st < NB; st <<= 1) {
        uint32_t v = (tid >= st && tid < NB) ? sdata[tid - st] : 0u;
        __syncthreads();
        if (tid < NB) sdata[tid] += v;
        __syncthreads();
    }
    if (tid == 0) s_M = (int)sdata[NB-1];
    if (tid < NB) {
        uint32_t M   = sdata[NB-1];
        uint32_t ge  = sdata[NB-1 - tid];
        uint32_t geN = (tid < NB-1) ? sdata[NB-2 - tid] : 0u;
        if (M >= TOPK && ge >= TOPK && geN < TOPK) s_T = tid;   // unique
    }
    __syncthreads();
    int T = s_T;
    int M = s_M;
    int npos = M < TOPK ? M : TOPK;

    // --- 3. gather candidates with bin >= T from buckets >= T>>4 ---
    {
        const uint32_t* gbcnt = (const uint32_t*)(ws + OFF_BCNT);
        const uint2* cand0 = (const uint2*)(ws + OFF_CAND);
        int cT = T >> 4;
        int W = NBKT - cT;
        for (int pIdx = tid; pIdx < NBLK1 * W; pIdx += 1024) {
            int blk = pIdx / W;
            int bkt = cT + (pIdx - blk * W);
            uint32_t cnt = gbcnt[blk*NBKT + bkt];
            const uint2* cb = cand0 + ((size_t)blk*NBKT + bkt) * SLOTB;
            for (uint32_t j = 0; j < cnt; ++j) {
                uint2 e = cb[j];
                float v = __uint_as_float(e.x);
                if (fine_bin(v) >= T) {
                    int slot = atomicAdd(&s_c2, 1);
                    if (slot < CCAP) { sc_v[slot] = v; sc_i[slot] = (int)e.y; }
                }
            }
        }
        __syncthreads();
    }

    // --- 4. exact rank (desc value, asc flat index = jax tie-break) ---
    {
        int C2 = s_c2; if (C2 > CCAP) C2 = CCAP;
        for (int e = tid; e < C2; e += 1024) {
            float vi = sc_v[e]; int xi = sc_i[e];
            int rank = 0;
            for (int j = 0; j < C2; ++j) {
                float vj = sc_v[j]; int xj = sc_i[j];
                rank += (vj > vi) || (vj == vi && xj < xi);
            }
            if (rank < npos) s_posI[rank] = xi;
        }
        __syncthreads();
    }

    // --- 5. total negatives ---
    {
        const uint32_t* gchunk = (const uint32_t*)(ws + OFF_CHUNK);
        sdata[tid] = (tid < NCHUNK) ? gchunk[tid] : 0u;
        __syncthreads();
        for (int st = 512; st > 0; st >>= 1) {
            if (tid < st) sdata[tid] += sdata[tid + st];
            __syncthreads();
        }
        if (tid == 0) s_negTot = (int)sdata[0];
        __syncthreads();
    }

    // --- 6. first TOPK neg positions (chunked scan, early exit) ---
    {
        const uint8_t* flags = ws + OFF_FLAG;
        int base = 0;
        for (int ch = 0; ch < NCHUNK && base < TOPK; ++ch) {
            int idx = ch*1024 + tid;
            uint32_t f = flags[idx];
            uint32_t ic = incl_scan(sdata, tid, f);
            int total = (int)sdata[1023];
            if (f && (base + (int)ic - 1) < TOPK) s_negI[base + ic - 1] = idx;
            __syncthreads();
            base += total;
        }
        __syncthreads();
    }

    // --- 7. write 100 x 20 output ---
    int i = tid;
    if (i >= TOPK) return;
    int negCount = s_negTot;
    float o[20];
    #pragma unroll
    for (int k = 0; k < 20; ++k) o[k] = 0.0f;

    if (i < npos) {
        int flat = s_posI[i];
        int a = flat % AA; int t = flat / AA;
        int g = t % GG; int bhw = t / GG;
        int pbase = (bhw * AA + a) * 4;
        float y1 = props[pbase+0], x1 = props[pbase+1];
        float y2 = props[pbase+2], x2 = props[pbase+3];
        float gy1 = s_gt[g*4+0], gx1 = s_gt[g*4+1];
        float gy2 = s_gt[g*4+2], gx2 = s_gt[g*4+3];
        float pcy = (y1 + y2) * 0.5f, pcx = (x1 + x2) * 0.5f;
        float ph = y2 - y1, pw = x2 - x1;
        float gcy = (gy1 + gy2) * 0.5f, gcx = (gx1 + gx2) * 0.5f;
        float gh = gy2 - gy1, gw = gx2 - gx1;
        int cbase = bhw * (2*AA) + 2*a;
        o[0] = pcy; o[1] = pcx; o[2] = ph; o[3] = pw;
        o[4] = cls[cbase]; o[5] = cls[cbase+1];
        o[6] = gcy; o[7] = gcx; o[8] = gh; o[9] = gw;
        o[10] = 1.0f; o[11] = 0.0f;
        if (i < negCount) {
            int nf = s_negI[i];
            int na = nf % AA; int nbhw = nf / AA;
            int nbase = nbhw * (2*AA) + 2*na;
            o[12] = cls[nbase]; o[13] = cls[nbase+1];
            o[14] = 0.0f; o[15] = 1.0f;
        }
        o[16] = (gcy - pcy) / ph;
        o[17] = (gcx - pcx) / pw;
        o[18] = (gh - ph) / ph;
        o[19] = (gw - pw) / pw;
    }
    #pragma unroll
    for (int k = 0; k < 20; ++k) out[i*20 + k] = o[k];
}

extern "C" void kernel_launch(void* const* d_in, const int* in_sizes, int n_in,
                              void* d_out, int out_size, void* d_ws, size_t ws_size,
                              hipStream_t stream) {
    (void)in_sizes; (void)n_in; (void)out_size; (void)ws_size;
    const float* props = (const float*)d_in[0];
    // d_in[1] = anchors (unused by the reference forward)
    const float* gt  = (const float*)d_in[2];
    const float* cls = (const float*)d_in[3];
    uint8_t* ws = (uint8_t*)d_ws;

    k_main<<<NBLK1, 1024, 0, stream>>>((const float4*)props, (const float4*)gt, ws);
    k_finish<<<1, 1024, 0, stream>>>(props, gt, cls, ws, (float*)d_out);
}

// Round 16
// 45.413 us; speedup vs baseline: 1.0366x; 1.0366x over previous
//
#include <hip/hip_runtime.h>
#include <stdint.h>

#define BB 4
#define HH 128
#define WW 128
#define AA 15
#define GG 32
#define NPOS (BB*HH*WW*AA)       // 983040
#define NBLK1 240                // k_main blocks (1 per CU, 4096 pos each)
#define POSB 4096
#define NCHUNK (NPOS/1024)       // 960
#define NB 256                   // fine bins over (0.5, 1.0]
#define NBKT 16                  // coarse buckets = NB/16
#define SLOTB 2048               // slots per (block,bucket)
#define TOPK 100
#define CCAP 2048

// workspace layout (bytes) — identical to r5/r13/r14 (proven). Everything
// k_finish reads is written unconditionally by k_main each call -> no zero-init.
#define OFF_CHUNK 0              // uint32[960]
#define OFF_FLAG  4096           // uint8[NPOS]
#define OFF_HISTB 987136         // uint32[240*256]
#define OFF_BCNT  1232896        // uint32[240*16]
#define OFF_CAND  1248256        // uint2[240*16*2048]  (~63 MB)

__device__ __forceinline__ int fine_bin(float v) {
    int b = (int)__builtin_fmaf(v, 512.0f, -256.0f);
    b = b < 0 ? 0 : (b > NB-1 ? NB-1 : b);
    return b;
}

// Pass 1 — r14 byte-identical (empirical optimum: full g-unroll, s_ga hoist,
// u-free screen). Screen: inter > 0.28*(area_p+area_g) <=> v > ~0.3889,
// conservative (every pair with exact v >= 0.4 passes); u = apga - inter is
// bit-identical to the reference's (area_p + area_g) - inter.
__global__ __launch_bounds__(1024) void k_main(const float4* __restrict__ props,
                                               const float4* __restrict__ gt4,
                                               uint8_t* __restrict__ ws) {
    __shared__ float4 s_gt4[GG];
    __shared__ float  s_ga[GG];
    __shared__ uint32_t s_hist[NB];
    __shared__ uint32_t s_bcnt[NBKT];
    __shared__ uint32_t s_red[64];
    int tid = threadIdx.x;
    if (tid < GG) s_gt4[tid] = gt4[tid];
    if (tid < NB) s_hist[tid] = 0u;
    if (tid < NBKT) s_bcnt[tid] = 0u;
    __syncthreads();
    if (tid < GG) {
        float4 G = s_gt4[tid];
        s_ga[tid] = (G.z - G.x) * (G.w - G.y);     // identical expr to reference
    }
    __syncthreads();

    uint2* candB = (uint2*)(ws + OFF_CAND) + (size_t)blockIdx.x * NBKT * SLOTB;

    for (int k = 0; k < 4; ++k) {
        int pos = blockIdx.x * POSB + k*1024 + tid;
        float4 p = props[pos];                      // (y1,x1,y2,x2)
        float area_p = (p.z - p.x) * (p.w - p.y);
        int bhw = pos / AA;
        int a = pos - bhw * AA;
        bool neg = true;
        #pragma unroll
        for (int g = 0; g < GG; ++g) {
            float4 G = s_gt4[g];
            float ih = fmaxf(fminf(p.z, G.z) - fmaxf(p.x, G.x), 0.0f);
            float iw = fmaxf(fminf(p.w, G.w) - fmaxf(p.y, G.y), 0.0f);
            float inter = ih * iw;
            float apga = area_p + s_ga[g];          // == reference (area_p+area_g)
            if (inter > 0.28f * apga) {
                float u = apga - inter;             // bit-identical reference u
                float v = inter / u;                // exact reference value
                neg = neg && (v < 0.4f);
                if (v > 0.5f) {
                    int bin = fine_bin(v);
                    atomicAdd(&s_hist[bin], 1u);    // UNCAPPED count
                    int bkt = bin >> 4;
                    uint32_t slot = atomicAdd(&s_bcnt[bkt], 1u);
                    if (slot < SLOTB)
                        candB[bkt*SLOTB + slot] =
                            make_uint2(__float_as_uint(v),
                                       (uint32_t)((bhw*GG + g)*AA + a));
                }
            }
        }
        ws[OFF_FLAG + pos] = neg ? 1 : 0;
        unsigned long long bal = __ballot(neg);
        if ((tid & 63) == 0) s_red[k*16 + (tid >> 6)] = (uint32_t)__popcll(bal);
    }
    __syncthreads();
    if (tid < 4) {
        uint32_t s = 0;
        #pragma unroll
        for (int w = 0; w < 16; ++w) s += s_red[tid*16 + w];
        ((uint32_t*)(ws + OFF_CHUNK))[blockIdx.x*4 + tid] = s;
    }
    if (tid < NB) ((uint32_t*)(ws + OFF_HISTB))[blockIdx.x*NB + tid] = s_hist[tid];
    if (tid < NBKT) {
        uint32_t c = s_bcnt[tid]; if (c > SLOTB) c = SLOTB;
        ((uint32_t*)(ws + OFF_BCNT))[blockIdx.x*NBKT + tid] = c;
    }
}

__device__ __forceinline__ uint32_t incl_scan(uint32_t* s, int tid, uint32_t v) {
    s[tid] = v; __syncthreads();
    for (int st = 1; st < 1024; st <<= 1) {
        uint32_t t = (tid >= st) ? s[tid - st] : 0u;
        __syncthreads();
        s[tid] += t;
        __syncthreads();
    }
    return s[tid];
}

// Pass 2 (r5/r13/r14-verbatim, proven): hist-sum -> T/npos, gather+rank,
// negatives, output.
__global__ __launch_bounds__(1024) void k_finish(const float* __restrict__ props,
                                                 const float* __restrict__ gt,
                                                 const float* __restrict__ cls,
                                                 uint8_t* __restrict__ ws,
                                                 float* __restrict__ out) {
    __shared__ uint32_t sdata[1024];
    __shared__ uint32_t s_tot[NB];
    __shared__ float sc_v[CCAP];
    __shared__ int   sc_i[CCAP];
    __shared__ int s_posI[128];
    __shared__ int s_negI[128];
    __shared__ float s_gt[GG*4];
    __shared__ int s_T, s_M, s_c2, s_negTot;

    int tid = threadIdx.x;
    if (tid < GG*4) s_gt[tid] = gt[tid];
    if (tid == 0) { s_T = 0; s_c2 = 0; }

    // --- 1. total histogram: 4 partial sums of 60 blocks each ---
    {
        const uint32_t* histB = (const uint32_t*)(ws + OFF_HISTB);
        int part = tid >> 8;          // 0..3
        int t = tid & 255;
        uint32_t ssum = 0;
        for (int blk = part*60; blk < part*60 + 60; ++blk) ssum += histB[blk*NB + t];
        sdata[tid] = ssum;
        __syncthreads();
        if (tid < NB) s_tot[tid] = sdata[tid] + sdata[tid+256] + sdata[tid+512] + sdata[tid+768];
        __syncthreads();
    }

    // --- 2. suffix counts -> M, T ---
    if (tid < NB) sdata[tid] = s_tot[NB-1 - tid];     // reversed
    __syncthreads();
    for (int st = 1; st < NB; st <<= 1) {
        uint32_t v = (tid >= st && tid < NB) ? sdata[tid - st] : 0u;
        __syncthreads();
        if (tid < NB) sdata[tid] += v;
        __syncthreads();
    }
    if (tid == 0) s_M = (int)sdata[NB-1];
    if (tid < NB) {
        uint32_t M   = sdata[NB-1];
        uint32_t ge  = sdata[NB-1 - tid];
        uint32_t geN = (tid < NB-1) ? sdata[NB-2 - tid] : 0u;
        if (M >= TOPK && ge >= TOPK && geN < TOPK) s_T = tid;   // unique
    }
    __syncthreads();
    int T = s_T;
    int M = s_M;
    int npos = M < TOPK ? M : TOPK;

    // --- 3. gather candidates with bin >= T from buckets >= T>>4 ---
    {
        const uint32_t* gbcnt = (const uint32_t*)(ws + OFF_BCNT);
        const uint2* cand0 = (const uint2*)(ws + OFF_CAND);
        int cT = T >> 4;
        int W = NBKT - cT;
        for (int pIdx = tid; pIdx < NBLK1 * W; pIdx += 1024) {
            int blk = pIdx / W;
            int bkt = cT + (pIdx - blk * W);
            uint32_t cnt = gbcnt[blk*NBKT + bkt];
            const uint2* cb = cand0 + ((size_t)blk*NBKT + bkt) * SLOTB;
            for (uint32_t j = 0; j < cnt; ++j) {
                uint2 e = cb[j];
                float v = __uint_as_float(e.x);
                if (fine_bin(v) >= T) {
                    int slot = atomicAdd(&s_c2, 1);
                    if (slot < CCAP) { sc_v[slot] = v; sc_i[slot] = (int)e.y; }
                }
            }
        }
        __syncthreads();
    }

    // --- 4. exact rank (desc value, asc flat index = jax tie-break) ---
    {
        int C2 = s_c2; if (C2 > CCAP) C2 = CCAP;
        for (int e = tid; e < C2; e += 1024) {
            float vi = sc_v[e]; int xi = sc_i[e];
            int rank = 0;
            for (int j = 0; j < C2; ++j) {
                float vj = sc_v[j]; int xj = sc_i[j];
                rank += (vj > vi) || (vj == vi && xj < xi);
            }
            if (rank < npos) s_posI[rank] = xi;
        }
        __syncthreads();
    }

    // --- 5. total negatives ---
    {
        const uint32_t* gchunk = (const uint32_t*)(ws + OFF_CHUNK);
        sdata[tid] = (tid < NCHUNK) ? gchunk[tid] : 0u;
        __syncthreads();
        for (int st = 512; st > 0; st >>= 1) {
            if (tid < st) sdata[tid] += sdata[tid + st];
            __syncthreads();
        }
        if (tid == 0) s_negTot = (int)sdata[0];
        __syncthreads();
    }

    // --- 6. first TOPK neg positions (chunked scan, early exit) ---
    {
        const uint8_t* flags = ws + OFF_FLAG;
        int base = 0;
        for (int ch = 0; ch < NCHUNK && base < TOPK; ++ch) {
            int idx = ch*1024 + tid;
            uint32_t f = flags[idx];
            uint32_t ic = incl_scan(sdata, tid, f);
            int total = (int)sdata[1023];
            if (f && (base + (int)ic - 1) < TOPK) s_negI[base + ic - 1] = idx;
            __syncthreads();
            base += total;
        }
        __syncthreads();
    }

    // --- 7. write 100 x 20 output ---
    int i = tid;
    if (i >= TOPK) return;
    int negCount = s_negTot;
    float o[20];
    #pragma unroll
    for (int k = 0; k < 20; ++k) o[k] = 0.0f;

    if (i < npos) {
        int flat = s_posI[i];
        int a = flat % AA; int t = flat / AA;
        int g = t % GG; int bhw = t / GG;
        int pbase = (bhw * AA + a) * 4;
        float y1 = props[pbase+0], x1 = props[pbase+1];
        float y2 = props[pbase+2], x2 = props[pbase+3];
        float gy1 = s_gt[g*4+0], gx1 = s_gt[g*4+1];
        float gy2 = s_gt[g*4+2], gx2 = s_gt[g*4+3];
        float pcy = (y1 + y2) * 0.5f, pcx = (x1 + x2) * 0.5f;
        float ph = y2 - y1, pw = x2 - x1;
        float gcy = (gy1 + gy2) * 0.5f, gcx = (gx1 + gx2) * 0.5f;
        float gh = gy2 - gy1, gw = gx2 - gx1;
        int cbase = bhw * (2*AA) + 2*a;
        o[0] = pcy; o[1] = pcx; o[2] = ph; o[3] = pw;
        o[4] = cls[cbase]; o[5] = cls[cbase+1];
        o[6] = gcy; o[7] = gcx; o[8] = gh; o[9] = gw;
        o[10] = 1.0f; o[11] = 0.0f;
        if (i < negCount) {
            int nf = s_negI[i];
            int na = nf % AA; int nbhw = nf / AA;
            int nbase = nbhw * (2*AA) + 2*na;
            o[12] = cls[nbase]; o[13] = cls[nbase+1];
            o[14] = 0.0f; o[15] = 1.0f;
        }
        o[16] = (gcy - pcy) / ph;
        o[17] = (gcx - pcx) / pw;
        o[18] = (gh - ph) / ph;
        o[19] = (gw - pw) / pw;
    }
    #pragma unroll
    for (int k = 0; k < 20; ++k) out[i*20 + k] = o[k];
}

extern "C" void kernel_launch(void* const* d_in, const int* in_sizes, int n_in,
                              void* d_out, int out_size, void* d_ws, size_t ws_size,
                              hipStream_t stream) {
    (void)in_sizes; (void)n_in; (void)out_size; (void)ws_size;
    const float* props = (const float*)d_in[0];
    // d_in[1] = anchors (unused by the reference forward)
    const float* gt  = (const float*)d_in[2];
    const float* cls = (const float*)d_in[3];
    uint8_t* ws = (uint8_t*)d_ws;

    k_main<<<NBLK1, 1024, 0, stream>>>((const float4*)props, (const float4*)gt, ws);
    k_finish<<<1, 1024, 0, stream>>>(props, gt, cls, ws, (float*)d_out);
}